// Round 10
// baseline (415.253 us; speedup 1.0000x reference)
//
#include <hip/hip_runtime.h>
#include <hip/hip_bf16.h>
#include <math.h>

// ---------------------------------------------------------------------------
// 3-layer GCN (PyG GCNConv semantics) on MI355X.
//   R2: packed u64 atomic per edge for degree (memory-side atomics halved).
//   R4: agg_k 16-lane-group float4 gathers (latency-bound fix #1).
//   R5: fill_csr atomics eliminated via edge_pass atomicAdd return (rank).
//   R8: ILP deepening across the three latency-bound kernels —
//       edge_pass/fill_csr 8 edges/thread (8 RMW/gather chains in flight),
//       agg_k unroll 8 + dual accumulators (8 float4 gathers in flight).
// ---------------------------------------------------------------------------

#define MASK44 ((1ull << 44) - 1)

__global__ __launch_bounds__(256) void init_k(unsigned long long* packed, int N) {
    int i = blockIdx.x * blockDim.x + threadIdx.x;
    if (i < N) packed[i] = 0ull;
}

// one packed atomic per edge: (1<<44) + w * 2^32; old>>44 = rank within bucket
// 8 edges/thread: 8 independent memory-side RMW round-trips in flight.
__global__ __launch_bounds__(256) void edge_pass_k(const int* __restrict__ dst,
                                                   const float* __restrict__ w,
                                                   unsigned long long* __restrict__ packed,
                                                   int* __restrict__ rank, int E) {
    int t = blockIdx.x * blockDim.x + threadIdx.x;
    int e = t * 8;
    if (e + 7 < E) {
        int4   da = *(const int4*)(dst + e);
        int4   db = *(const int4*)(dst + e + 4);
        float4 wa = *(const float4*)(w + e);
        float4 wb = *(const float4*)(w + e + 4);
        unsigned long long o0 = atomicAdd(&packed[da.x], (1ull << 44) + (unsigned long long)((double)wa.x * 4294967296.0));
        unsigned long long o1 = atomicAdd(&packed[da.y], (1ull << 44) + (unsigned long long)((double)wa.y * 4294967296.0));
        unsigned long long o2 = atomicAdd(&packed[da.z], (1ull << 44) + (unsigned long long)((double)wa.z * 4294967296.0));
        unsigned long long o3 = atomicAdd(&packed[da.w], (1ull << 44) + (unsigned long long)((double)wa.w * 4294967296.0));
        unsigned long long o4 = atomicAdd(&packed[db.x], (1ull << 44) + (unsigned long long)((double)wb.x * 4294967296.0));
        unsigned long long o5 = atomicAdd(&packed[db.y], (1ull << 44) + (unsigned long long)((double)wb.y * 4294967296.0));
        unsigned long long o6 = atomicAdd(&packed[db.z], (1ull << 44) + (unsigned long long)((double)wb.z * 4294967296.0));
        unsigned long long o7 = atomicAdd(&packed[db.w], (1ull << 44) + (unsigned long long)((double)wb.w * 4294967296.0));
        *(int4*)(rank + e)     = make_int4((int)(o0 >> 44), (int)(o1 >> 44),
                                           (int)(o2 >> 44), (int)(o3 >> 44));
        *(int4*)(rank + e + 4) = make_int4((int)(o4 >> 44), (int)(o5 >> 44),
                                           (int)(o6 >> 44), (int)(o7 >> 44));
    } else {
        for (int k = e; k < E; ++k) {
            unsigned long long o =
                atomicAdd(&packed[dst[k]], (1ull << 44) + (unsigned long long)((double)w[k] * 4294967296.0));
            rank[k] = (int)(o >> 44);
        }
    }
}

// block-level exclusive scan of counts (from packed) + fused dinv computation
__global__ __launch_bounds__(1024) void scan_block_k(const unsigned long long* __restrict__ packed,
                                                     float* __restrict__ dinv,
                                                     int* __restrict__ tmp,
                                                     int* __restrict__ bsum, int N) {
    __shared__ int sm[1024];
    int tid = threadIdx.x;
    int g = blockIdx.x * 1024 + tid;
    unsigned long long pk = (g < N) ? packed[g] : 0ull;
    int v = (int)(pk >> 44);
    if (g < N) {
        double deg = 1.0 + (double)(pk & MASK44) * (1.0 / 4294967296.0);   // >= 1 always
        dinv[g] = (float)(1.0 / sqrt(deg));
    }
    sm[tid] = v;
    __syncthreads();
    for (int off = 1; off < 1024; off <<= 1) {
        int t = (tid >= off) ? sm[tid - off] : 0;
        __syncthreads();
        sm[tid] += t;
        __syncthreads();
    }
    if (g < N) tmp[g] = sm[tid] - v;          // exclusive within block
    if (tid == 1023) bsum[blockIdx.x] = sm[1023];
}

// single-block parallel exclusive scan of the (<=1024) block sums
__global__ __launch_bounds__(1024) void scan_bsums_k(int* bsum, int nb, int* rowptr, int N) {
    __shared__ int sm[1024];
    int tid = threadIdx.x;
    int v = (tid < nb) ? bsum[tid] : 0;
    sm[tid] = v;
    __syncthreads();
    for (int off = 1; off < 1024; off <<= 1) {
        int t = (tid >= off) ? sm[tid - off] : 0;
        __syncthreads();
        sm[tid] += t;
        __syncthreads();
    }
    if (tid < nb) bsum[tid] = sm[tid] - v;
    if (tid == 1023) rowptr[N] = sm[1023];
}

__global__ __launch_bounds__(1024) void scan_add_k(const int* __restrict__ tmp,
                                                   const int* __restrict__ bsum,
                                                   int* __restrict__ rowptr, int N) {
    int g = blockIdx.x * 1024 + threadIdx.x;
    if (g < N) rowptr[g] = tmp[g] + bsum[blockIdx.x];
}

// CSR fill, atomic-free: pos = rowptr[dst] + rank. 8 edges/thread.
__global__ __launch_bounds__(256) void fill_csr_k(const int* __restrict__ src,
                                                  const int* __restrict__ dst,
                                                  const float* __restrict__ w,
                                                  const float* __restrict__ dinv,
                                                  const int* __restrict__ rowptr,
                                                  const int* __restrict__ rank,
                                                  int2* __restrict__ csr, int E) {
    int t = blockIdx.x * blockDim.x + threadIdx.x;
    int e = t * 8;
    if (e + 7 < E) {
        int4   sa = *(const int4*)(src + e);
        int4   sb = *(const int4*)(src + e + 4);
        int4   da = *(const int4*)(dst + e);
        int4   db = *(const int4*)(dst + e + 4);
        int4   ra = *(const int4*)(rank + e);
        int4   rb = *(const int4*)(rank + e + 4);
        float4 wa = *(const float4*)(w + e);
        float4 wb = *(const float4*)(w + e + 4);
        int p0 = rowptr[da.x] + ra.x;
        int p1 = rowptr[da.y] + ra.y;
        int p2 = rowptr[da.z] + ra.z;
        int p3 = rowptr[da.w] + ra.w;
        int p4 = rowptr[db.x] + rb.x;
        int p5 = rowptr[db.y] + rb.y;
        int p6 = rowptr[db.z] + rb.z;
        int p7 = rowptr[db.w] + rb.w;
        csr[p0] = make_int2(sa.x, __float_as_int(dinv[sa.x] * wa.x * dinv[da.x]));
        csr[p1] = make_int2(sa.y, __float_as_int(dinv[sa.y] * wa.y * dinv[da.y]));
        csr[p2] = make_int2(sa.z, __float_as_int(dinv[sa.z] * wa.z * dinv[da.z]));
        csr[p3] = make_int2(sa.w, __float_as_int(dinv[sa.w] * wa.w * dinv[da.w]));
        csr[p4] = make_int2(sb.x, __float_as_int(dinv[sb.x] * wb.x * dinv[db.x]));
        csr[p5] = make_int2(sb.y, __float_as_int(dinv[sb.y] * wb.y * dinv[db.y]));
        csr[p6] = make_int2(sb.z, __float_as_int(dinv[sb.z] * wb.z * dinv[db.z]));
        csr[p7] = make_int2(sb.w, __float_as_int(dinv[sb.w] * wb.w * dinv[db.w]));
    } else {
        for (int k = e; k < E; ++k) {
            int d = dst[k], s = src[k];
            int pos = rowptr[d] + rank[k];
            csr[pos] = make_int2(s, __float_as_int(dinv[s] * w[k] * dinv[d]));
        }
    }
}

// ---- GEMM: H[N,64] = X[N,64] @ W[64,64] (fp32, no MFMA on CDNA4) ----
__global__ __launch_bounds__(256) void gemm64_k(const float* __restrict__ X,
                                                const float* __restrict__ W,
                                                float* __restrict__ H, int N) {
    __shared__ float Wl[64 * 64];   // row-major W[k][c]
    __shared__ float Xl[64 * 68];   // X[row][k], stride 68 (bank-spread)
    int tid = threadIdx.x;
    for (int i = tid; i < 4096; i += 256) Wl[i] = W[i];
    int row0 = blockIdx.x * 64;
    {
        int r = tid >> 6, c = tid & 63;
        #pragma unroll
        for (int p = 0; p < 16; ++p) {
            int rr = r + 4 * p;
            int grow = row0 + rr;
            Xl[rr * 68 + c] = (grow < N) ? X[(size_t)grow * 64 + c] : 0.0f;
        }
    }
    __syncthreads();
    int tc = tid & 15, tr = tid >> 4;
    float acc[4][4];
    #pragma unroll
    for (int i = 0; i < 4; ++i)
        #pragma unroll
        for (int j = 0; j < 4; ++j) acc[i][j] = 0.0f;

    #pragma unroll 8
    for (int k = 0; k < 64; ++k) {
        float4 wv = *(const float4*)&Wl[k * 64 + 4 * tc];
        float x0 = Xl[(4 * tr + 0) * 68 + k];
        float x1 = Xl[(4 * tr + 1) * 68 + k];
        float x2 = Xl[(4 * tr + 2) * 68 + k];
        float x3 = Xl[(4 * tr + 3) * 68 + k];
        acc[0][0] += x0 * wv.x; acc[0][1] += x0 * wv.y; acc[0][2] += x0 * wv.z; acc[0][3] += x0 * wv.w;
        acc[1][0] += x1 * wv.x; acc[1][1] += x1 * wv.y; acc[1][2] += x1 * wv.z; acc[1][3] += x1 * wv.w;
        acc[2][0] += x2 * wv.x; acc[2][1] += x2 * wv.y; acc[2][2] += x2 * wv.z; acc[2][3] += x2 * wv.w;
        acc[3][0] += x3 * wv.x; acc[3][1] += x3 * wv.y; acc[3][2] += x3 * wv.z; acc[3][3] += x3 * wv.w;
    }
    #pragma unroll
    for (int i = 0; i < 4; ++i) {
        int grow = row0 + 4 * tr + i;
        if (grow < N) {
            float4 st = make_float4(acc[i][0], acc[i][1], acc[i][2], acc[i][3]);
            *(float4*)&H[(size_t)grow * 64 + 4 * tc] = st;
        }
    }
}

// ---- aggregation: one wave per node; 4 edges/iter via 16-lane groups ----
// unroll 8 + dual accumulators: up to 8 float4 gathers in flight per lane.
__global__ __launch_bounds__(256) void agg_k(const float* __restrict__ H,
                                             const int* __restrict__ rowptr,
                                             const int2* __restrict__ csr,
                                             const float* __restrict__ dinv,
                                             const float* __restrict__ bias,
                                             float* __restrict__ out, int N) {
    int wave = (blockIdx.x * blockDim.x + threadIdx.x) >> 6;
    int lane = threadIdx.x & 63;
    if (wave >= N) return;
    int i = wave;
    int g = lane >> 4;        // 0..3  edge slot
    int l = lane & 15;        // 0..15 feature quad

    float di = dinv[i];
    // self loop (norm = dinv^2), counted once via group 0
    float4 acc0, acc1;
    {
        float4 hv = *(const float4*)&H[(size_t)i * 64 + 4 * l];
        float s = (g == 0) ? (di * di) : 0.0f;
        acc0.x = hv.x * s; acc0.y = hv.y * s; acc0.z = hv.z * s; acc0.w = hv.w * s;
        acc1.x = 0.0f; acc1.y = 0.0f; acc1.z = 0.0f; acc1.w = 0.0f;
    }

    int e0 = rowptr[i], e1 = rowptr[i + 1];
    int e = e0;
    while (e < e1) {
        int nb = e1 - e;
        if (nb > 64) nb = 64;
        int2 m = (lane < nb) ? csr[e + lane] : make_int2(0, 0);   // pad: norm=0
        #pragma unroll 4
        for (int j = 0; j < nb; j += 8) {
            int   sl0 = j + g;
            int   sj0 = __shfl(m.x, sl0);
            float nj0 = __shfl(__int_as_float(m.y), sl0);
            int   has1 = (j + 4 < nb);
            int   sl1 = has1 ? (j + 4 + g) : sl0;
            int   sj1 = __shfl(m.x, sl1);
            float nj1 = has1 ? __shfl(__int_as_float(m.y), sl1) : 0.0f;
            float4 hv0 = *(const float4*)&H[(size_t)sj0 * 64 + 4 * l];
            float4 hv1 = *(const float4*)&H[(size_t)sj1 * 64 + 4 * l];
            acc0.x += hv0.x * nj0; acc0.y += hv0.y * nj0;
            acc0.z += hv0.z * nj0; acc0.w += hv0.w * nj0;
            acc1.x += hv1.x * nj1; acc1.y += hv1.y * nj1;
            acc1.z += hv1.z * nj1; acc1.w += hv1.w * nj1;
        }
        e += nb;
    }

    float4 acc;
    acc.x = acc0.x + acc1.x; acc.y = acc0.y + acc1.y;
    acc.z = acc0.z + acc1.z; acc.w = acc0.w + acc1.w;

    // reduce across the 4 groups (xor 16, then 32)
    acc.x += __shfl_xor(acc.x, 16); acc.y += __shfl_xor(acc.y, 16);
    acc.z += __shfl_xor(acc.z, 16); acc.w += __shfl_xor(acc.w, 16);
    acc.x += __shfl_xor(acc.x, 32); acc.y += __shfl_xor(acc.y, 32);
    acc.z += __shfl_xor(acc.z, 32); acc.w += __shfl_xor(acc.w, 32);

    if (g == 0) {
        float4 bv = *(const float4*)&bias[4 * l];
        float4 st;
        st.x = fmaxf(acc.x + bv.x, 0.0f);
        st.y = fmaxf(acc.y + bv.y, 0.0f);
        st.z = fmaxf(acc.z + bv.z, 0.0f);
        st.w = fmaxf(acc.w + bv.w, 0.0f);
        *(float4*)&out[(size_t)i * 64 + 4 * l] = st;
    }
}

// ---------------------------------------------------------------------------

extern "C" void kernel_launch(void* const* d_in, const int* in_sizes, int n_in,
                              void* d_out, int out_size, void* d_ws, size_t ws_size,
                              hipStream_t stream) {
    const float* x   = (const float*)d_in[0];
    const int*   ei  = (const int*)d_in[1];
    const float* ew  = (const float*)d_in[2];
    const float* W1  = (const float*)d_in[3];
    const float* b1  = (const float*)d_in[4];
    const float* W2  = (const float*)d_in[5];
    const float* b2  = (const float*)d_in[6];
    const float* W3  = (const float*)d_in[7];
    const float* b3  = (const float*)d_in[8];
    float* out = (float*)d_out;

    const int N = in_sizes[0] / 64;         // 100000
    const int E = in_sizes[1] / 2;          // 1200000
    const int* src = ei;
    const int* dst = ei + E;

    // ---- workspace carve-up (all 256B-aligned) ----
    char* p = (char*)d_ws;
    size_t off = 0;
    auto carve = [&](size_t bytes) -> void* {
        void* q = p + off;
        off += (bytes + 255) & ~(size_t)255;
        return q;
    };
    unsigned long long* packed = (unsigned long long*)carve((size_t)N * 8);
    float* dinv   = (float*)carve((size_t)N * 4);
    int*   tmp    = (int*)  carve((size_t)N * 4);
    int*   rowptr = (int*)  carve((size_t)(N + 1) * 4);
    int*   bsum   = (int*)  carve((size_t)1024 * 4);
    int*   rank   = (int*)  carve((size_t)E * 4);
    int2*  csr    = (int2*) carve((size_t)E * 8);
    float* Hbuf   = (float*)carve((size_t)N * 64 * 4);
    float* Abuf   = (float*)carve((size_t)N * 64 * 4);
    (void)ws_size;

    const int nB  = (N + 255) / 256;
    const int e8B = ((E + 7) / 8 + 255) / 256;      // 8 edges/thread
    const int nb  = (N + 1023) / 1024;              // scan blocks (98 for N=100K)
    const int gB  = (N + 63) / 64;                  // gemm blocks (64 rows each)
    const int aB  = (N * 64 + 255) / 256;           // agg blocks (4 waves each)

    // preprocessing
    init_k<<<nB, 256, 0, stream>>>(packed, N);
    edge_pass_k<<<e8B, 256, 0, stream>>>(dst, ew, packed, rank, E);
    scan_block_k<<<nb, 1024, 0, stream>>>(packed, dinv, tmp, bsum, N);
    scan_bsums_k<<<1, 1024, 0, stream>>>(bsum, nb, rowptr, N);
    scan_add_k<<<nb, 1024, 0, stream>>>(tmp, bsum, rowptr, N);
    fill_csr_k<<<e8B, 256, 0, stream>>>(src, dst, ew, dinv, rowptr, rank, csr, E);

    // layer 1: H = x @ W1 ; A = relu(agg(H) + b1)
    gemm64_k<<<gB, 256, 0, stream>>>(x, W1, Hbuf, N);
    agg_k<<<aB, 256, 0, stream>>>(Hbuf, rowptr, csr, dinv, b1, Abuf, N);
    // layer 2
    gemm64_k<<<gB, 256, 0, stream>>>(Abuf, W2, Hbuf, N);
    agg_k<<<aB, 256, 0, stream>>>(Hbuf, rowptr, csr, dinv, b2, Abuf, N);
    // layer 3 -> d_out
    gemm64_k<<<gB, 256, 0, stream>>>(Abuf, W3, Hbuf, N);
    agg_k<<<aB, 256, 0, stream>>>(Hbuf, rowptr, csr, dinv, b3, out, N);
}

// Round 11
// 400.474 us; speedup vs baseline: 1.0369x; 1.0369x over previous
//
#include <hip/hip_runtime.h>
#include <hip/hip_bf16.h>
#include <math.h>

// ---------------------------------------------------------------------------
// 3-layer GCN (PyG GCNConv semantics) on MI355X.
//   R2: packed u64 atomic per edge for degree (memory-side atomics halved).
//   R4: agg_k 16-lane-group float4 gathers.
//   R5: fill_csr atomics eliminated via edge_pass atomicAdd return (rank).
//   R8: 8 edges/thread ILP (edge_pass flat -> atomic service-rate bound).
//   R10: overlap & launch-count reduction — layer-1 GEMM fused into the
//        edge_pass dispatch (role-split interleaved grid: gemm VALU work
//        hides under atomic latency); bsums scan fused into scan_add.
//        12 -> 10 dispatches.
// ---------------------------------------------------------------------------

#define MASK44 ((1ull << 44) - 1)

__global__ __launch_bounds__(256) void init_k(unsigned long long* packed, int N) {
    int i = blockIdx.x * blockDim.x + threadIdx.x;
    if (i < N) packed[i] = 0ull;
}

// ---- fused: edge_pass (atomic rank/degree) + layer-1 GEMM ----
// grid is grouped in 11s: r<8 -> gemm role, r>=8 -> edge role (72.7% / 27.3%
// matches 1563 gemm blocks : 586 edge blocks) so roles co-reside on each CU.
__global__ __launch_bounds__(256) void edge_gemm1_k(const int* __restrict__ dst,
                                                    const float* __restrict__ w,
                                                    unsigned long long* __restrict__ packed,
                                                    int* __restrict__ rank, int E,
                                                    const float* __restrict__ X,
                                                    const float* __restrict__ W1,
                                                    float* __restrict__ H, int N,
                                                    int gB, int eB) {
    __shared__ float Wl[64 * 64];
    __shared__ float Xl[64 * 68];
    int bid = blockIdx.x;
    int q = bid / 11, r = bid % 11;
    int tid = threadIdx.x;

    if (r < 8) {
        // ---------------- GEMM role ----------------
        int gb = q * 8 + r;
        if (gb >= gB) return;
        for (int i = tid; i < 4096; i += 256) Wl[i] = W1[i];
        int row0 = gb * 64;
        {
            int rr0 = tid >> 6, c = tid & 63;
            #pragma unroll
            for (int p = 0; p < 16; ++p) {
                int rr = rr0 + 4 * p;
                int grow = row0 + rr;
                Xl[rr * 68 + c] = (grow < N) ? X[(size_t)grow * 64 + c] : 0.0f;
            }
        }
        __syncthreads();
        int tc = tid & 15, tr = tid >> 4;
        float acc[4][4];
        #pragma unroll
        for (int i = 0; i < 4; ++i)
            #pragma unroll
            for (int j = 0; j < 4; ++j) acc[i][j] = 0.0f;
        #pragma unroll 8
        for (int k = 0; k < 64; ++k) {
            float4 wv = *(const float4*)&Wl[k * 64 + 4 * tc];
            float x0 = Xl[(4 * tr + 0) * 68 + k];
            float x1 = Xl[(4 * tr + 1) * 68 + k];
            float x2 = Xl[(4 * tr + 2) * 68 + k];
            float x3 = Xl[(4 * tr + 3) * 68 + k];
            acc[0][0] += x0 * wv.x; acc[0][1] += x0 * wv.y; acc[0][2] += x0 * wv.z; acc[0][3] += x0 * wv.w;
            acc[1][0] += x1 * wv.x; acc[1][1] += x1 * wv.y; acc[1][2] += x1 * wv.z; acc[1][3] += x1 * wv.w;
            acc[2][0] += x2 * wv.x; acc[2][1] += x2 * wv.y; acc[2][2] += x2 * wv.z; acc[2][3] += x2 * wv.w;
            acc[3][0] += x3 * wv.x; acc[3][1] += x3 * wv.y; acc[3][2] += x3 * wv.z; acc[3][3] += x3 * wv.w;
        }
        #pragma unroll
        for (int i = 0; i < 4; ++i) {
            int grow = row0 + 4 * tr + i;
            if (grow < N) {
                float4 st = make_float4(acc[i][0], acc[i][1], acc[i][2], acc[i][3]);
                *(float4*)&H[(size_t)grow * 64 + 4 * tc] = st;
            }
        }
    } else {
        // ---------------- edge role (packed atomic + rank capture) ----------
        int eb = q * 3 + (r - 8);
        if (eb >= eB) return;
        int t = eb * 256 + tid;
        int e = t * 8;
        if (e + 7 < E) {
            int4   da = *(const int4*)(dst + e);
            int4   db = *(const int4*)(dst + e + 4);
            float4 wa = *(const float4*)(w + e);
            float4 wb = *(const float4*)(w + e + 4);
            unsigned long long o0 = atomicAdd(&packed[da.x], (1ull << 44) + (unsigned long long)((double)wa.x * 4294967296.0));
            unsigned long long o1 = atomicAdd(&packed[da.y], (1ull << 44) + (unsigned long long)((double)wa.y * 4294967296.0));
            unsigned long long o2 = atomicAdd(&packed[da.z], (1ull << 44) + (unsigned long long)((double)wa.z * 4294967296.0));
            unsigned long long o3 = atomicAdd(&packed[da.w], (1ull << 44) + (unsigned long long)((double)wa.w * 4294967296.0));
            unsigned long long o4 = atomicAdd(&packed[db.x], (1ull << 44) + (unsigned long long)((double)wb.x * 4294967296.0));
            unsigned long long o5 = atomicAdd(&packed[db.y], (1ull << 44) + (unsigned long long)((double)wb.y * 4294967296.0));
            unsigned long long o6 = atomicAdd(&packed[db.z], (1ull << 44) + (unsigned long long)((double)wb.z * 4294967296.0));
            unsigned long long o7 = atomicAdd(&packed[db.w], (1ull << 44) + (unsigned long long)((double)wb.w * 4294967296.0));
            *(int4*)(rank + e)     = make_int4((int)(o0 >> 44), (int)(o1 >> 44),
                                               (int)(o2 >> 44), (int)(o3 >> 44));
            *(int4*)(rank + e + 4) = make_int4((int)(o4 >> 44), (int)(o5 >> 44),
                                               (int)(o6 >> 44), (int)(o7 >> 44));
        } else {
            for (int k = e; k < E; ++k) {
                unsigned long long o =
                    atomicAdd(&packed[dst[k]], (1ull << 44) + (unsigned long long)((double)w[k] * 4294967296.0));
                rank[k] = (int)(o >> 44);
            }
        }
    }
}

// block-level exclusive scan of counts (from packed) + fused dinv computation
__global__ __launch_bounds__(1024) void scan_block_k(const unsigned long long* __restrict__ packed,
                                                     float* __restrict__ dinv,
                                                     int* __restrict__ tmp,
                                                     int* __restrict__ bsum, int N) {
    __shared__ int sm[1024];
    int tid = threadIdx.x;
    int g = blockIdx.x * 1024 + tid;
    unsigned long long pk = (g < N) ? packed[g] : 0ull;
    int v = (int)(pk >> 44);
    if (g < N) {
        double deg = 1.0 + (double)(pk & MASK44) * (1.0 / 4294967296.0);   // >= 1 always
        dinv[g] = (float)(1.0 / sqrt(deg));
    }
    sm[tid] = v;
    __syncthreads();
    for (int off = 1; off < 1024; off <<= 1) {
        int t = (tid >= off) ? sm[tid - off] : 0;
        __syncthreads();
        sm[tid] += t;
        __syncthreads();
    }
    if (g < N) tmp[g] = sm[tid] - v;          // exclusive within block
    if (tid == 1023) bsum[blockIdx.x] = sm[1023];
}

// fused: every block redundantly scans the (<=128) block sums in LDS, then
// adds its prefix. Also writes rowptr[N] = grand total.
__global__ __launch_bounds__(1024) void scan_add_k(const int* __restrict__ tmp,
                                                   const int* __restrict__ bsum,
                                                   int* __restrict__ rowptr, int N, int nb) {
    __shared__ int sb[128];
    int tid = threadIdx.x;
    if (tid < 128) sb[tid] = (tid < nb) ? bsum[tid] : 0;
    __syncthreads();
    #pragma unroll
    for (int off = 1; off < 128; off <<= 1) {
        int v = (tid < 128 && tid >= off) ? sb[tid - off] : 0;
        __syncthreads();
        if (tid < 128) sb[tid] += v;
        __syncthreads();
    }
    int prefix = (blockIdx.x > 0) ? sb[blockIdx.x - 1] : 0;
    int g = blockIdx.x * 1024 + tid;
    if (g < N) rowptr[g] = tmp[g] + prefix;
    if (blockIdx.x == 0 && tid == 0) rowptr[N] = sb[nb - 1];
}

// CSR fill, atomic-free: pos = rowptr[dst] + rank. 8 edges/thread.
__global__ __launch_bounds__(256) void fill_csr_k(const int* __restrict__ src,
                                                  const int* __restrict__ dst,
                                                  const float* __restrict__ w,
                                                  const float* __restrict__ dinv,
                                                  const int* __restrict__ rowptr,
                                                  const int* __restrict__ rank,
                                                  int2* __restrict__ csr, int E) {
    int t = blockIdx.x * blockDim.x + threadIdx.x;
    int e = t * 8;
    if (e + 7 < E) {
        int4   sa = *(const int4*)(src + e);
        int4   sb = *(const int4*)(src + e + 4);
        int4   da = *(const int4*)(dst + e);
        int4   db = *(const int4*)(dst + e + 4);
        int4   ra = *(const int4*)(rank + e);
        int4   rb = *(const int4*)(rank + e + 4);
        float4 wa = *(const float4*)(w + e);
        float4 wb = *(const float4*)(w + e + 4);
        int p0 = rowptr[da.x] + ra.x;
        int p1 = rowptr[da.y] + ra.y;
        int p2 = rowptr[da.z] + ra.z;
        int p3 = rowptr[da.w] + ra.w;
        int p4 = rowptr[db.x] + rb.x;
        int p5 = rowptr[db.y] + rb.y;
        int p6 = rowptr[db.z] + rb.z;
        int p7 = rowptr[db.w] + rb.w;
        csr[p0] = make_int2(sa.x, __float_as_int(dinv[sa.x] * wa.x * dinv[da.x]));
        csr[p1] = make_int2(sa.y, __float_as_int(dinv[sa.y] * wa.y * dinv[da.y]));
        csr[p2] = make_int2(sa.z, __float_as_int(dinv[sa.z] * wa.z * dinv[da.z]));
        csr[p3] = make_int2(sa.w, __float_as_int(dinv[sa.w] * wa.w * dinv[da.w]));
        csr[p4] = make_int2(sb.x, __float_as_int(dinv[sb.x] * wb.x * dinv[db.x]));
        csr[p5] = make_int2(sb.y, __float_as_int(dinv[sb.y] * wb.y * dinv[db.y]));
        csr[p6] = make_int2(sb.z, __float_as_int(dinv[sb.z] * wb.z * dinv[db.z]));
        csr[p7] = make_int2(sb.w, __float_as_int(dinv[sb.w] * wb.w * dinv[db.w]));
    } else {
        for (int k = e; k < E; ++k) {
            int d = dst[k], s = src[k];
            int pos = rowptr[d] + rank[k];
            csr[pos] = make_int2(s, __float_as_int(dinv[s] * w[k] * dinv[d]));
        }
    }
}

// ---- GEMM: H[N,64] = X[N,64] @ W[64,64] (layers 2,3) ----
__global__ __launch_bounds__(256) void gemm64_k(const float* __restrict__ X,
                                                const float* __restrict__ W,
                                                float* __restrict__ H, int N) {
    __shared__ float Wl[64 * 64];
    __shared__ float Xl[64 * 68];
    int tid = threadIdx.x;
    for (int i = tid; i < 4096; i += 256) Wl[i] = W[i];
    int row0 = blockIdx.x * 64;
    {
        int r = tid >> 6, c = tid & 63;
        #pragma unroll
        for (int p = 0; p < 16; ++p) {
            int rr = r + 4 * p;
            int grow = row0 + rr;
            Xl[rr * 68 + c] = (grow < N) ? X[(size_t)grow * 64 + c] : 0.0f;
        }
    }
    __syncthreads();
    int tc = tid & 15, tr = tid >> 4;
    float acc[4][4];
    #pragma unroll
    for (int i = 0; i < 4; ++i)
        #pragma unroll
        for (int j = 0; j < 4; ++j) acc[i][j] = 0.0f;

    #pragma unroll 8
    for (int k = 0; k < 64; ++k) {
        float4 wv = *(const float4*)&Wl[k * 64 + 4 * tc];
        float x0 = Xl[(4 * tr + 0) * 68 + k];
        float x1 = Xl[(4 * tr + 1) * 68 + k];
        float x2 = Xl[(4 * tr + 2) * 68 + k];
        float x3 = Xl[(4 * tr + 3) * 68 + k];
        acc[0][0] += x0 * wv.x; acc[0][1] += x0 * wv.y; acc[0][2] += x0 * wv.z; acc[0][3] += x0 * wv.w;
        acc[1][0] += x1 * wv.x; acc[1][1] += x1 * wv.y; acc[1][2] += x1 * wv.z; acc[1][3] += x1 * wv.w;
        acc[2][0] += x2 * wv.x; acc[2][1] += x2 * wv.y; acc[2][2] += x2 * wv.z; acc[2][3] += x2 * wv.w;
        acc[3][0] += x3 * wv.x; acc[3][1] += x3 * wv.y; acc[3][2] += x3 * wv.z; acc[3][3] += x3 * wv.w;
    }
    #pragma unroll
    for (int i = 0; i < 4; ++i) {
        int grow = row0 + 4 * tr + i;
        if (grow < N) {
            float4 st = make_float4(acc[i][0], acc[i][1], acc[i][2], acc[i][3]);
            *(float4*)&H[(size_t)grow * 64 + 4 * tc] = st;
        }
    }
}

// ---- aggregation: one wave per node; 4 edges/iter via 16-lane groups ----
__global__ __launch_bounds__(256) void agg_k(const float* __restrict__ H,
                                             const int* __restrict__ rowptr,
                                             const int2* __restrict__ csr,
                                             const float* __restrict__ dinv,
                                             const float* __restrict__ bias,
                                             float* __restrict__ out, int N) {
    int wave = (blockIdx.x * blockDim.x + threadIdx.x) >> 6;
    int lane = threadIdx.x & 63;
    if (wave >= N) return;
    int i = wave;
    int g = lane >> 4;        // 0..3  edge slot
    int l = lane & 15;        // 0..15 feature quad

    float di = dinv[i];
    float4 acc0, acc1;
    {
        float4 hv = *(const float4*)&H[(size_t)i * 64 + 4 * l];
        float s = (g == 0) ? (di * di) : 0.0f;
        acc0.x = hv.x * s; acc0.y = hv.y * s; acc0.z = hv.z * s; acc0.w = hv.w * s;
        acc1.x = 0.0f; acc1.y = 0.0f; acc1.z = 0.0f; acc1.w = 0.0f;
    }

    int e0 = rowptr[i], e1 = rowptr[i + 1];
    int e = e0;
    while (e < e1) {
        int nb = e1 - e;
        if (nb > 64) nb = 64;
        int2 m = (lane < nb) ? csr[e + lane] : make_int2(0, 0);   // pad: norm=0
        #pragma unroll 4
        for (int j = 0; j < nb; j += 8) {
            int   sl0 = j + g;
            int   sj0 = __shfl(m.x, sl0);
            float nj0 = __shfl(__int_as_float(m.y), sl0);
            int   has1 = (j + 4 < nb);
            int   sl1 = has1 ? (j + 4 + g) : sl0;
            int   sj1 = __shfl(m.x, sl1);
            float nj1 = has1 ? __shfl(__int_as_float(m.y), sl1) : 0.0f;
            float4 hv0 = *(const float4*)&H[(size_t)sj0 * 64 + 4 * l];
            float4 hv1 = *(const float4*)&H[(size_t)sj1 * 64 + 4 * l];
            acc0.x += hv0.x * nj0; acc0.y += hv0.y * nj0;
            acc0.z += hv0.z * nj0; acc0.w += hv0.w * nj0;
            acc1.x += hv1.x * nj1; acc1.y += hv1.y * nj1;
            acc1.z += hv1.z * nj1; acc1.w += hv1.w * nj1;
        }
        e += nb;
    }

    float4 acc;
    acc.x = acc0.x + acc1.x; acc.y = acc0.y + acc1.y;
    acc.z = acc0.z + acc1.z; acc.w = acc0.w + acc1.w;

    acc.x += __shfl_xor(acc.x, 16); acc.y += __shfl_xor(acc.y, 16);
    acc.z += __shfl_xor(acc.z, 16); acc.w += __shfl_xor(acc.w, 16);
    acc.x += __shfl_xor(acc.x, 32); acc.y += __shfl_xor(acc.y, 32);
    acc.z += __shfl_xor(acc.z, 32); acc.w += __shfl_xor(acc.w, 32);

    if (g == 0) {
        float4 bv = *(const float4*)&bias[4 * l];
        float4 st;
        st.x = fmaxf(acc.x + bv.x, 0.0f);
        st.y = fmaxf(acc.y + bv.y, 0.0f);
        st.z = fmaxf(acc.z + bv.z, 0.0f);
        st.w = fmaxf(acc.w + bv.w, 0.0f);
        *(float4*)&out[(size_t)i * 64 + 4 * l] = st;
    }
}

// ---------------------------------------------------------------------------

extern "C" void kernel_launch(void* const* d_in, const int* in_sizes, int n_in,
                              void* d_out, int out_size, void* d_ws, size_t ws_size,
                              hipStream_t stream) {
    const float* x   = (const float*)d_in[0];
    const int*   ei  = (const int*)d_in[1];
    const float* ew  = (const float*)d_in[2];
    const float* W1  = (const float*)d_in[3];
    const float* b1  = (const float*)d_in[4];
    const float* W2  = (const float*)d_in[5];
    const float* b2  = (const float*)d_in[6];
    const float* W3  = (const float*)d_in[7];
    const float* b3  = (const float*)d_in[8];
    float* out = (float*)d_out;

    const int N = in_sizes[0] / 64;         // 100000
    const int E = in_sizes[1] / 2;          // 1200000
    const int* src = ei;
    const int* dst = ei + E;

    // ---- workspace carve-up (all 256B-aligned) ----
    char* p = (char*)d_ws;
    size_t off = 0;
    auto carve = [&](size_t bytes) -> void* {
        void* q = p + off;
        off += (bytes + 255) & ~(size_t)255;
        return q;
    };
    unsigned long long* packed = (unsigned long long*)carve((size_t)N * 8);
    float* dinv   = (float*)carve((size_t)N * 4);
    int*   tmp    = (int*)  carve((size_t)N * 4);
    int*   rowptr = (int*)  carve((size_t)(N + 1) * 4);
    int*   bsum   = (int*)  carve((size_t)1024 * 4);
    int*   rank   = (int*)  carve((size_t)E * 4);
    int2*  csr    = (int2*) carve((size_t)E * 8);
    float* Hbuf   = (float*)carve((size_t)N * 64 * 4);
    float* Abuf   = (float*)carve((size_t)N * 64 * 4);
    (void)ws_size;

    const int nB  = (N + 255) / 256;
    const int eB  = ((E + 7) / 8 + 255) / 256;      // edge blocks (586)
    const int gB  = (N + 63) / 64;                  // gemm blocks (1563)
    const int nb  = (N + 1023) / 1024;              // scan blocks (98)
    const int aB  = (N * 64 + 255) / 256;           // agg blocks (4 waves each)
    const int fuseGroups = ((gB + 7) / 8 > (eB + 2) / 3) ? (gB + 7) / 8 : (eB + 2) / 3;
    const int fB  = fuseGroups * 11;                // fused edge+gemm1 grid

    // preprocessing + layer-1 GEMM overlapped
    init_k<<<nB, 256, 0, stream>>>(packed, N);
    edge_gemm1_k<<<fB, 256, 0, stream>>>(dst, ew, packed, rank, E,
                                         x, W1, Hbuf, N, gB, eB);
    scan_block_k<<<nb, 1024, 0, stream>>>(packed, dinv, tmp, bsum, N);
    scan_add_k<<<nb, 1024, 0, stream>>>(tmp, bsum, rowptr, N, nb);
    fill_csr_k<<<eB, 256, 0, stream>>>(src, dst, ew, dinv, rowptr, rank, csr, E);

    // layer 1 aggregation (Hbuf already produced by fused kernel)
    agg_k<<<aB, 256, 0, stream>>>(Hbuf, rowptr, csr, dinv, b1, Abuf, N);
    // layer 2
    gemm64_k<<<gB, 256, 0, stream>>>(Abuf, W2, Hbuf, N);
    agg_k<<<aB, 256, 0, stream>>>(Hbuf, rowptr, csr, dinv, b2, Abuf, N);
    // layer 3 -> d_out
    gemm64_k<<<gB, 256, 0, stream>>>(Abuf, W3, Hbuf, N);
    agg_k<<<aB, 256, 0, stream>>>(Hbuf, rowptr, csr, dinv, b3, out, N);
}

// Round 13
// 397.296 us; speedup vs baseline: 1.0452x; 1.0080x over previous
//
#include <hip/hip_runtime.h>
#include <hip/hip_bf16.h>
#include <math.h>

// ---------------------------------------------------------------------------
// 3-layer GCN (PyG GCNConv semantics) on MI355X.
//   R2: packed u64 atomic per edge for degree.
//   R4: agg_k 16-lane-group float4 gathers.
//   R5: fill_csr atomics eliminated via edge_pass atomicAdd return (rank).
//   R8: 8 edges/thread ILP (edge_pass flat -> atomic service-rate bound).
//   R10: layer-1 GEMM fused into edge_pass dispatch; scan fused. (-15us but
//        zero overlap: 33.8KB LDS -> 4 blocks/CU starved edge concurrency.)
//   R11: fused-kernel occupancy fix — W read from global (L1-resident 16KB),
//        LDS 33.8->17.4KB (9 blocks/CU); edge-role blocks FIRST in grid
//        order so the atomic pipe saturates immediately.
// ---------------------------------------------------------------------------

#define MASK44 ((1ull << 44) - 1)

__global__ __launch_bounds__(256) void init_k(unsigned long long* packed, int N) {
    int i = blockIdx.x * blockDim.x + threadIdx.x;
    if (i < N) packed[i] = 0ull;
}

// ---- fused: edge_pass (atomic rank/degree) + layer-1 GEMM ----
// groups of 11: r<3 -> edge role (dispatched first within group), r>=3 -> gemm.
__global__ __launch_bounds__(256) void edge_gemm1_k(const int* __restrict__ dst,
                                                    const float* __restrict__ w,
                                                    unsigned long long* __restrict__ packed,
                                                    int* __restrict__ rank, int E,
                                                    const float* __restrict__ X,
                                                    const float* __restrict__ W1,
                                                    float* __restrict__ H, int N,
                                                    int gB, int eB) {
    __shared__ float Xl[64 * 68];   // 17.4 KB total -> 9 blocks/CU
    int bid = blockIdx.x;
    int q = bid / 11, r = bid % 11;
    int tid = threadIdx.x;

    if (r >= 3) {
        // ---------------- GEMM role ----------------
        int gb = q * 8 + (r - 3);
        if (gb >= gB) return;
        int row0 = gb * 64;
        {
            int rr0 = tid >> 6, c = tid & 63;
            #pragma unroll
            for (int p = 0; p < 16; ++p) {
                int rr = rr0 + 4 * p;
                int grow = row0 + rr;
                Xl[rr * 68 + c] = (grow < N) ? X[(size_t)grow * 64 + c] : 0.0f;
            }
        }
        __syncthreads();
        int tc = tid & 15, tr = tid >> 4;
        float acc[4][4];
        #pragma unroll
        for (int i = 0; i < 4; ++i)
            #pragma unroll
            for (int j = 0; j < 4; ++j) acc[i][j] = 0.0f;
        #pragma unroll 8
        for (int k = 0; k < 64; ++k) {
            float4 wv = *(const float4*)&W1[k * 64 + 4 * tc];   // L1-resident 16KB
            float x0 = Xl[(4 * tr + 0) * 68 + k];
            float x1 = Xl[(4 * tr + 1) * 68 + k];
            float x2 = Xl[(4 * tr + 2) * 68 + k];
            float x3 = Xl[(4 * tr + 3) * 68 + k];
            acc[0][0] += x0 * wv.x; acc[0][1] += x0 * wv.y; acc[0][2] += x0 * wv.z; acc[0][3] += x0 * wv.w;
            acc[1][0] += x1 * wv.x; acc[1][1] += x1 * wv.y; acc[1][2] += x1 * wv.z; acc[1][3] += x1 * wv.w;
            acc[2][0] += x2 * wv.x; acc[2][1] += x2 * wv.y; acc[2][2] += x2 * wv.z; acc[2][3] += x2 * wv.w;
            acc[3][0] += x3 * wv.x; acc[3][1] += x3 * wv.y; acc[3][2] += x3 * wv.z; acc[3][3] += x3 * wv.w;
        }
        #pragma unroll
        for (int i = 0; i < 4; ++i) {
            int grow = row0 + 4 * tr + i;
            if (grow < N) {
                float4 st = make_float4(acc[i][0], acc[i][1], acc[i][2], acc[i][3]);
                *(float4*)&H[(size_t)grow * 64 + 4 * tc] = st;
            }
        }
    } else {
        // ---------------- edge role (packed atomic + rank capture) ----------
        int eb = q * 3 + r;
        if (eb >= eB) return;
        int t = eb * 256 + tid;
        int e = t * 8;
        if (e + 7 < E) {
            int4   da = *(const int4*)(dst + e);
            int4   db = *(const int4*)(dst + e + 4);
            float4 wa = *(const float4*)(w + e);
            float4 wb = *(const float4*)(w + e + 4);
            unsigned long long o0 = atomicAdd(&packed[da.x], (1ull << 44) + (unsigned long long)((double)wa.x * 4294967296.0));
            unsigned long long o1 = atomicAdd(&packed[da.y], (1ull << 44) + (unsigned long long)((double)wa.y * 4294967296.0));
            unsigned long long o2 = atomicAdd(&packed[da.z], (1ull << 44) + (unsigned long long)((double)wa.z * 4294967296.0));
            unsigned long long o3 = atomicAdd(&packed[da.w], (1ull << 44) + (unsigned long long)((double)wa.w * 4294967296.0));
            unsigned long long o4 = atomicAdd(&packed[db.x], (1ull << 44) + (unsigned long long)((double)wb.x * 4294967296.0));
            unsigned long long o5 = atomicAdd(&packed[db.y], (1ull << 44) + (unsigned long long)((double)wb.y * 4294967296.0));
            unsigned long long o6 = atomicAdd(&packed[db.z], (1ull << 44) + (unsigned long long)((double)wb.z * 4294967296.0));
            unsigned long long o7 = atomicAdd(&packed[db.w], (1ull << 44) + (unsigned long long)((double)wb.w * 4294967296.0));
            *(int4*)(rank + e)     = make_int4((int)(o0 >> 44), (int)(o1 >> 44),
                                               (int)(o2 >> 44), (int)(o3 >> 44));
            *(int4*)(rank + e + 4) = make_int4((int)(o4 >> 44), (int)(o5 >> 44),
                                               (int)(o6 >> 44), (int)(o7 >> 44));
        } else {
            for (int k = e; k < E; ++k) {
                unsigned long long o =
                    atomicAdd(&packed[dst[k]], (1ull << 44) + (unsigned long long)((double)w[k] * 4294967296.0));
                rank[k] = (int)(o >> 44);
            }
        }
    }
}

// block-level exclusive scan of counts (from packed) + fused dinv computation
__global__ __launch_bounds__(1024) void scan_block_k(const unsigned long long* __restrict__ packed,
                                                     float* __restrict__ dinv,
                                                     int* __restrict__ tmp,
                                                     int* __restrict__ bsum, int N) {
    __shared__ int sm[1024];
    int tid = threadIdx.x;
    int g = blockIdx.x * 1024 + tid;
    unsigned long long pk = (g < N) ? packed[g] : 0ull;
    int v = (int)(pk >> 44);
    if (g < N) {
        double deg = 1.0 + (double)(pk & MASK44) * (1.0 / 4294967296.0);   // >= 1 always
        dinv[g] = (float)(1.0 / sqrt(deg));
    }
    sm[tid] = v;
    __syncthreads();
    for (int off = 1; off < 1024; off <<= 1) {
        int t = (tid >= off) ? sm[tid - off] : 0;
        __syncthreads();
        sm[tid] += t;
        __syncthreads();
    }
    if (g < N) tmp[g] = sm[tid] - v;          // exclusive within block
    if (tid == 1023) bsum[blockIdx.x] = sm[1023];
}

// fused: every block redundantly scans the (<=128) block sums in LDS, then
// adds its prefix. Also writes rowptr[N] = grand total.
__global__ __launch_bounds__(1024) void scan_add_k(const int* __restrict__ tmp,
                                                   const int* __restrict__ bsum,
                                                   int* __restrict__ rowptr, int N, int nb) {
    __shared__ int sb[128];
    int tid = threadIdx.x;
    if (tid < 128) sb[tid] = (tid < nb) ? bsum[tid] : 0;
    __syncthreads();
    #pragma unroll
    for (int off = 1; off < 128; off <<= 1) {
        int v = (tid < 128 && tid >= off) ? sb[tid - off] : 0;
        __syncthreads();
        if (tid < 128) sb[tid] += v;
        __syncthreads();
    }
    int prefix = (blockIdx.x > 0) ? sb[blockIdx.x - 1] : 0;
    int g = blockIdx.x * 1024 + tid;
    if (g < N) rowptr[g] = tmp[g] + prefix;
    if (blockIdx.x == 0 && tid == 0) rowptr[N] = sb[nb - 1];
}

// CSR fill, atomic-free: pos = rowptr[dst] + rank. 8 edges/thread.
__global__ __launch_bounds__(256) void fill_csr_k(const int* __restrict__ src,
                                                  const int* __restrict__ dst,
                                                  const float* __restrict__ w,
                                                  const float* __restrict__ dinv,
                                                  const int* __restrict__ rowptr,
                                                  const int* __restrict__ rank,
                                                  int2* __restrict__ csr, int E) {
    int t = blockIdx.x * blockDim.x + threadIdx.x;
    int e = t * 8;
    if (e + 7 < E) {
        int4   sa = *(const int4*)(src + e);
        int4   sb = *(const int4*)(src + e + 4);
        int4   da = *(const int4*)(dst + e);
        int4   db = *(const int4*)(dst + e + 4);
        int4   ra = *(const int4*)(rank + e);
        int4   rb = *(const int4*)(rank + e + 4);
        float4 wa = *(const float4*)(w + e);
        float4 wb = *(const float4*)(w + e + 4);
        int p0 = rowptr[da.x] + ra.x;
        int p1 = rowptr[da.y] + ra.y;
        int p2 = rowptr[da.z] + ra.z;
        int p3 = rowptr[da.w] + ra.w;
        int p4 = rowptr[db.x] + rb.x;
        int p5 = rowptr[db.y] + rb.y;
        int p6 = rowptr[db.z] + rb.z;
        int p7 = rowptr[db.w] + rb.w;
        csr[p0] = make_int2(sa.x, __float_as_int(dinv[sa.x] * wa.x * dinv[da.x]));
        csr[p1] = make_int2(sa.y, __float_as_int(dinv[sa.y] * wa.y * dinv[da.y]));
        csr[p2] = make_int2(sa.z, __float_as_int(dinv[sa.z] * wa.z * dinv[da.z]));
        csr[p3] = make_int2(sa.w, __float_as_int(dinv[sa.w] * wa.w * dinv[da.w]));
        csr[p4] = make_int2(sb.x, __float_as_int(dinv[sb.x] * wb.x * dinv[db.x]));
        csr[p5] = make_int2(sb.y, __float_as_int(dinv[sb.y] * wb.y * dinv[db.y]));
        csr[p6] = make_int2(sb.z, __float_as_int(dinv[sb.z] * wb.z * dinv[db.z]));
        csr[p7] = make_int2(sb.w, __float_as_int(dinv[sb.w] * wb.w * dinv[db.w]));
    } else {
        for (int k = e; k < E; ++k) {
            int d = dst[k], s = src[k];
            int pos = rowptr[d] + rank[k];
            csr[pos] = make_int2(s, __float_as_int(dinv[s] * w[k] * dinv[d]));
        }
    }
}

// ---- GEMM: H[N,64] = X[N,64] @ W[64,64] (layers 2,3) — W from L1/global ----
__global__ __launch_bounds__(256) void gemm64_k(const float* __restrict__ X,
                                                const float* __restrict__ W,
                                                float* __restrict__ H, int N) {
    __shared__ float Xl[64 * 68];
    int tid = threadIdx.x;
    int row0 = blockIdx.x * 64;
    {
        int r = tid >> 6, c = tid & 63;
        #pragma unroll
        for (int p = 0; p < 16; ++p) {
            int rr = r + 4 * p;
            int grow = row0 + rr;
            Xl[rr * 68 + c] = (grow < N) ? X[(size_t)grow * 64 + c] : 0.0f;
        }
    }
    __syncthreads();
    int tc = tid & 15, tr = tid >> 4;
    float acc[4][4];
    #pragma unroll
    for (int i = 0; i < 4; ++i)
        #pragma unroll
        for (int j = 0; j < 4; ++j) acc[i][j] = 0.0f;

    #pragma unroll 8
    for (int k = 0; k < 64; ++k) {
        float4 wv = *(const float4*)&W[k * 64 + 4 * tc];
        float x0 = Xl[(4 * tr + 0) * 68 + k];
        float x1 = Xl[(4 * tr + 1) * 68 + k];
        float x2 = Xl[(4 * tr + 2) * 68 + k];
        float x3 = Xl[(4 * tr + 3) * 68 + k];
        acc[0][0] += x0 * wv.x; acc[0][1] += x0 * wv.y; acc[0][2] += x0 * wv.z; acc[0][3] += x0 * wv.w;
        acc[1][0] += x1 * wv.x; acc[1][1] += x1 * wv.y; acc[1][2] += x1 * wv.z; acc[1][3] += x1 * wv.w;
        acc[2][0] += x2 * wv.x; acc[2][1] += x2 * wv.y; acc[2][2] += x2 * wv.z; acc[2][3] += x2 * wv.w;
        acc[3][0] += x3 * wv.x; acc[3][1] += x3 * wv.y; acc[3][2] += x3 * wv.z; acc[3][3] += x3 * wv.w;
    }
    #pragma unroll
    for (int i = 0; i < 4; ++i) {
        int grow = row0 + 4 * tr + i;
        if (grow < N) {
            float4 st = make_float4(acc[i][0], acc[i][1], acc[i][2], acc[i][3]);
            *(float4*)&H[(size_t)grow * 64 + 4 * tc] = st;
        }
    }
}

// ---- aggregation: one wave per node; 4 edges/iter via 16-lane groups ----
__global__ __launch_bounds__(256) void agg_k(const float* __restrict__ H,
                                             const int* __restrict__ rowptr,
                                             const int2* __restrict__ csr,
                                             const float* __restrict__ dinv,
                                             const float* __restrict__ bias,
                                             float* __restrict__ out, int N) {
    int wave = (blockIdx.x * blockDim.x + threadIdx.x) >> 6;
    int lane = threadIdx.x & 63;
    if (wave >= N) return;
    int i = wave;
    int g = lane >> 4;        // 0..3  edge slot
    int l = lane & 15;        // 0..15 feature quad

    float di = dinv[i];
    float4 acc0, acc1;
    {
        float4 hv = *(const float4*)&H[(size_t)i * 64 + 4 * l];
        float s = (g == 0) ? (di * di) : 0.0f;
        acc0.x = hv.x * s; acc0.y = hv.y * s; acc0.z = hv.z * s; acc0.w = hv.w * s;
        acc1.x = 0.0f; acc1.y = 0.0f; acc1.z = 0.0f; acc1.w = 0.0f;
    }

    int e0 = rowptr[i], e1 = rowptr[i + 1];
    int e = e0;
    while (e < e1) {
        int nb = e1 - e;
        if (nb > 64) nb = 64;
        int2 m = (lane < nb) ? csr[e + lane] : make_int2(0, 0);   // pad: norm=0
        #pragma unroll 4
        for (int j = 0; j < nb; j += 8) {
            int   sl0 = j + g;
            int   sj0 = __shfl(m.x, sl0);
            float nj0 = __shfl(__int_as_float(m.y), sl0);
            int   has1 = (j + 4 < nb);
            int   sl1 = has1 ? (j + 4 + g) : sl0;
            int   sj1 = __shfl(m.x, sl1);
            float nj1 = has1 ? __shfl(__int_as_float(m.y), sl1) : 0.0f;
            float4 hv0 = *(const float4*)&H[(size_t)sj0 * 64 + 4 * l];
            float4 hv1 = *(const float4*)&H[(size_t)sj1 * 64 + 4 * l];
            acc0.x += hv0.x * nj0; acc0.y += hv0.y * nj0;
            acc0.z += hv0.z * nj0; acc0.w += hv0.w * nj0;
            acc1.x += hv1.x * nj1; acc1.y += hv1.y * nj1;
            acc1.z += hv1.z * nj1; acc1.w += hv1.w * nj1;
        }
        e += nb;
    }

    float4 acc;
    acc.x = acc0.x + acc1.x; acc.y = acc0.y + acc1.y;
    acc.z = acc0.z + acc1.z; acc.w = acc0.w + acc1.w;

    acc.x += __shfl_xor(acc.x, 16); acc.y += __shfl_xor(acc.y, 16);
    acc.z += __shfl_xor(acc.z, 16); acc.w += __shfl_xor(acc.w, 16);
    acc.x += __shfl_xor(acc.x, 32); acc.y += __shfl_xor(acc.y, 32);
    acc.z += __shfl_xor(acc.z, 32); acc.w += __shfl_xor(acc.w, 32);

    if (g == 0) {
        float4 bv = *(const float4*)&bias[4 * l];
        float4 st;
        st.x = fmaxf(acc.x + bv.x, 0.0f);
        st.y = fmaxf(acc.y + bv.y, 0.0f);
        st.z = fmaxf(acc.z + bv.z, 0.0f);
        st.w = fmaxf(acc.w + bv.w, 0.0f);
        *(float4*)&out[(size_t)i * 64 + 4 * l] = st;
    }
}

// ---------------------------------------------------------------------------

extern "C" void kernel_launch(void* const* d_in, const int* in_sizes, int n_in,
                              void* d_out, int out_size, void* d_ws, size_t ws_size,
                              hipStream_t stream) {
    const float* x   = (const float*)d_in[0];
    const int*   ei  = (const int*)d_in[1];
    const float* ew  = (const float*)d_in[2];
    const float* W1  = (const float*)d_in[3];
    const float* b1  = (const float*)d_in[4];
    const float* W2  = (const float*)d_in[5];
    const float* b2  = (const float*)d_in[6];
    const float* W3  = (const float*)d_in[7];
    const float* b3  = (const float*)d_in[8];
    float* out = (float*)d_out;

    const int N = in_sizes[0] / 64;         // 100000
    const int E = in_sizes[1] / 2;          // 1200000
    const int* src = ei;
    const int* dst = ei + E;

    // ---- workspace carve-up (all 256B-aligned) ----
    char* p = (char*)d_ws;
    size_t off = 0;
    auto carve = [&](size_t bytes) -> void* {
        void* q = p + off;
        off += (bytes + 255) & ~(size_t)255;
        return q;
    };
    unsigned long long* packed = (unsigned long long*)carve((size_t)N * 8);
    float* dinv   = (float*)carve((size_t)N * 4);
    int*   tmp    = (int*)  carve((size_t)N * 4);
    int*   rowptr = (int*)  carve((size_t)(N + 1) * 4);
    int*   bsum   = (int*)  carve((size_t)1024 * 4);
    int*   rank   = (int*)  carve((size_t)E * 4);
    int2*  csr    = (int2*) carve((size_t)E * 8);
    float* Hbuf   = (float*)carve((size_t)N * 64 * 4);
    float* Abuf   = (float*)carve((size_t)N * 64 * 4);
    (void)ws_size;

    const int nB  = (N + 255) / 256;
    const int eB  = ((E + 7) / 8 + 255) / 256;      // edge blocks (586)
    const int gB  = (N + 63) / 64;                  // gemm blocks (1563)
    const int nb  = (N + 1023) / 1024;              // scan blocks (98)
    const int aB  = (N * 64 + 255) / 256;           // agg blocks (4 waves each)
    const int fuseGroups = ((gB + 7) / 8 > (eB + 2) / 3) ? (gB + 7) / 8 : (eB + 2) / 3;
    const int fB  = fuseGroups * 11;                // fused edge+gemm1 grid

    // preprocessing + layer-1 GEMM overlapped
    init_k<<<nB, 256, 0, stream>>>(packed, N);
    edge_gemm1_k<<<fB, 256, 0, stream>>>(dst, ew, packed, rank, E,
                                         x, W1, Hbuf, N, gB, eB);
    scan_block_k<<<nb, 1024, 0, stream>>>(packed, dinv, tmp, bsum, N);
    scan_add_k<<<nb, 1024, 0, stream>>>(tmp, bsum, rowptr, N, nb);
    fill_csr_k<<<eB, 256, 0, stream>>>(src, dst, ew, dinv, rowptr, rank, csr, E);

    // layer 1 aggregation (Hbuf already produced by fused kernel)
    agg_k<<<aB, 256, 0, stream>>>(Hbuf, rowptr, csr, dinv, b1, Abuf, N);
    // layer 2
    gemm64_k<<<gB, 256, 0, stream>>>(Abuf, W2, Hbuf, N);
    agg_k<<<aB, 256, 0, stream>>>(Hbuf, rowptr, csr, dinv, b2, Abuf, N);
    // layer 3 -> d_out
    gemm64_k<<<gB, 256, 0, stream>>>(Abuf, W3, Hbuf, N);
    agg_k<<<aB, 256, 0, stream>>>(Hbuf, rowptr, csr, dinv, b3, out, N);
}